// Round 9
// baseline (277.745 us; speedup 1.0000x reference)
//
#include <hip/hip_runtime.h>
#include <math.h>

// ProtoPNet forward on MI355X (gfx950).
// out concat: [x (6422528) | min_dists (128000) | dists (25088000) | activations (128000) | logits (12800)]

#define EPSV 1e-4f
typedef unsigned short ushort_t;

constexpr int NB  = 64;
constexpr int NC  = 512;
constexpr int NHW = 196;
constexpr int NP  = 2000;
constexpr int NPAD = 2048;
constexpr int NCL = 200;
constexpr int MM   = NB * NHW;        // 12544 = 98*128
constexpr int XTOT = NB * NC * NHW;   // 6422528

constexpr long long OFF_MIN = XTOT;
constexpr long long OFF_D   = OFF_MIN + (long long)NB * NP;
constexpr long long OFF_ACT = OFF_D + (long long)NB * NP * NHW;
constexpr long long OFF_LOG = OFF_ACT + (long long)NB * NP;

typedef __attribute__((ext_vector_type(8))) short short8;
typedef __attribute__((ext_vector_type(4))) float f32x4;

__device__ __forceinline__ unsigned bf16rne(float f) {
    unsigned u = __float_as_uint(f);
    return (u + 0x7FFFu + ((u >> 16) & 1u)) >> 16;
}

__device__ __forceinline__ void gl_lds16(const void* g, void* l) {
    __builtin_amdgcn_global_load_lds(
        (const __attribute__((address_space(1))) unsigned int*)g,
        (__attribute__((address_space(3))) unsigned int*)l, 16, 0, 0);
}

// ---------- proto -> ph [2048][512] bf16 (zero-pad, PRE-SWIZZLED per 64-chunk) + p2
//            ALSO: init mind=+MAX, x2=0 (runs FIRST) ----------
__global__ __launch_bounds__(256) void splitp_kernel(const float* __restrict__ proto,
                              ushort_t* __restrict__ ph, float* __restrict__ p2,
                              float* __restrict__ mind, float* __restrict__ x2) {
    int gi = blockIdx.x * 256 + threadIdx.x;      // < 131072
    if (gi < NB * NP) mind[gi] = 3.402823466e38f;
    if (gi < MM)      x2[gi]  = 0.f;

    int p = blockIdx.x * 4 + (threadIdx.x >> 6);  // < 2048
    int l = threadIdx.x & 63;                     // slot index (8 elems each)
    unsigned hs[8];
    float s = 0.f;
    if (p < NP) {
        const float4* pr = (const float4*)(proto + (size_t)p * NC + l * 8);
        float4 a = pr[0], bb = pr[1];
        float vv[8] = {a.x, a.y, a.z, a.w, bb.x, bb.y, bb.z, bb.w};
        #pragma unroll
        for (int k = 0; k < 8; ++k) { hs[k] = bf16rne(vv[k]); s += vv[k] * vv[k]; }
    } else {
        #pragma unroll
        for (int k = 0; k < 8; ++k) hs[k] = 0;
    }
    uint4 H = make_uint4(hs[0] | (hs[1] << 16), hs[2] | (hs[3] << 16),
                         hs[4] | (hs[5] << 16), hs[6] | (hs[7] << 16));
    // swizzle within 64-elem chunk: chunk = l>>3, slot-in-chunk = l&7 -> ^ (p&7)
    int col = (l >> 3) * 64 + (((l & 7) ^ (p & 7)) << 3);
    *(uint4*)&ph[(size_t)p * NC + col] = H;
    for (int off = 32; off; off >>= 1) s += __shfl_down(s, off, 64);
    if (l == 0) p2[p] = s;
}

// ---------- x -> xh [m][512] bf16 (transpose, PRE-SWIZZLED), x2 += partial,
//            optionally fused x passthrough copy (when xh lives in d_ws) ----------
__global__ __launch_bounds__(256) void splitx_kernel(const float* __restrict__ x,
                                                     ushort_t* __restrict__ xh,
                                                     float* __restrict__ x2,
                                                     float* __restrict__ xcopy,
                                                     int do_copy) {
    __shared__ float tl[64 * 197];
    const int b = blockIdx.x >> 3, cc = blockIdx.x & 7;
    const int c0 = cc * 64;
    const size_t gbase = ((size_t)b * NC + c0) * NHW;
    const float* src = x + gbase;
    for (int idx = threadIdx.x; idx < 64 * 196; idx += 256) {
        float v = src[idx];
        tl[(idx / 196) * 197 + (idx % 196)] = v;
        if (do_copy) __builtin_nontemporal_store(v, &xcopy[gbase + idx]);
    }
    __syncthreads();
    // phase 2: units = (hw, slot): 196*8 = 1568
    for (int idx = threadIdx.x; idx < 1568; idx += 256) {
        int hw = idx >> 3, slot = idx & 7;
        int m = b * 196 + hw;
        unsigned hs[8];
        #pragma unroll
        for (int e = 0; e < 8; ++e)
            hs[e] = bf16rne(tl[(slot * 8 + e) * 197 + hw]);
        uint4 H = make_uint4(hs[0] | (hs[1] << 16), hs[2] | (hs[3] << 16),
                             hs[4] | (hs[5] << 16), hs[6] | (hs[7] << 16));
        *(uint4*)&xh[(size_t)m * NC + c0 + ((slot ^ (m & 7)) << 3)] = H;
    }
    if (threadIdx.x < 196) {
        float s = 0.f;
        #pragma unroll 8
        for (int cl = 0; cl < 64; ++cl) { float v = tl[cl * 197 + threadIdx.x]; s += v * v; }
        atomicAdd(&x2[b * 196 + threadIdx.x], s);
    }
}

// ---------- main: bf16 MFMA GEMM + dists + fused min ----------
// 128x128 tile, BK=64, 2-phase double-buffered global_load_lds(16), XOR-swizzled LDS.
__global__ __launch_bounds__(256) void gemm_kernel(
    const ushort_t* __restrict__ xh, const ushort_t* __restrict__ ph,
    const float* __restrict__ p2, const float* __restrict__ x2,
    float* __restrict__ dists, unsigned* __restrict__ mind)
{
    __shared__ ushort_t Ah[2][128 * 64];
    __shared__ ushort_t Bh[2][128 * 64];

    // XCD-bijective swizzle: 1568 = 8*196; nt-slow within XCD (B-tiles L2-resident)
    const int wg  = blockIdx.x;
    const int swz = (wg & 7) * 196 + (wg >> 3);
    const int nt  = swz / 98, mt = swz - nt * 98;

    const int t = threadIdx.x;
    const int lane = t & 63, lm = lane & 15, kg = lane >> 4;
    const int w = t >> 6, wp = w >> 1, wx = w & 1;

    // staging: thread t -> (row = t>>3, slot = t&7); each issue covers 32 rows
    const size_t ga = (size_t)(mt * 128 + (t >> 3)) * NC + (t & 7) * 8;
    const size_t gb = (size_t)(nt * 128 + (t >> 3)) * NC + (t & 7) * 8;
    const size_t gs = (size_t)32 * NC;

#define STAGE(bufi, c0) do {                                            \
        _Pragma("unroll")                                               \
        for (int q = 0; q < 4; ++q) {                                   \
            gl_lds16(xh + ga + q * gs + (c0), &Ah[bufi][q * 2048 + t * 8]); \
            gl_lds16(ph + gb + q * gs + (c0), &Bh[bufi][q * 2048 + t * 8]); \
        } } while (0)

    f32x4 acc[4][4];
    #pragma unroll
    for (int i = 0; i < 4; ++i)
        #pragma unroll
        for (int j = 0; j < 4; ++j) acc[i][j] = 0.f;

    STAGE(0, 0);
    __syncthreads();                 // tile 0 resident

    for (int step = 0; step < 8; ++step) {
        const int cur = step & 1;
        if (step < 7) STAGE(cur ^ 1, (step + 1) * 64);   // issue next-tile loads (fly under MFMA)

        short8 PF[2][4], XF[2][4];
        #pragma unroll
        for (int s = 0; s < 2; ++s)
            #pragma unroll
            for (int i = 0; i < 4; ++i) {
                int prow = wp * 64 + i * 16 + lm;
                int xrow = wx * 64 + i * 16 + lm;
                int lsp = (s * 4 + kg) ^ (prow & 7);
                int lsx = (s * 4 + kg) ^ (xrow & 7);
                PF[s][i] = *(const short8*)&Bh[cur][prow * 64 + lsp * 8];
                XF[s][i] = *(const short8*)&Ah[cur][xrow * 64 + lsx * 8];
            }
        #pragma unroll
        for (int s = 0; s < 2; ++s)
            #pragma unroll
            for (int i = 0; i < 4; ++i)
                #pragma unroll
                for (int j = 0; j < 4; ++j)
                    acc[i][j] = __builtin_amdgcn_mfma_f32_16x16x32_bf16(PF[s][i], XF[s][j], acc[i][j], 0, 0, 0);
        __syncthreads();             // drains this step's stage; next buf ready
    }
#undef STAGE

    // epilogue: dists = relu(x2 - 2*xp + p2) (nontemporal), fused min -> atomics
    const int mhalf = mt * 128 + wx * 64;
    const int b0h = mhalf / 196;
    const int b1h = (mhalf + 63) / 196;
    float x2v[4]; int bj[4]; size_t dbase[4];
    #pragma unroll
    for (int j = 0; j < 4; ++j) {
        int m = mhalf + j * 16 + lm;
        x2v[j] = x2[m];
        int b = m / 196, hw = m - b * 196;
        bj[j] = b;
        dbase[j] = (size_t)b * ((size_t)NP * NHW) + hw;
    }
    #pragma unroll
    for (int i = 0; i < 4; ++i) {
        #pragma unroll
        for (int r = 0; r < 4; ++r) {
            int p = nt * 128 + wp * 64 + i * 16 + kg * 4 + r;
            if (p < NP) {
                float p2v = p2[p];
                float mn0 = 3.402823466e38f, mn1 = 3.402823466e38f;
                #pragma unroll
                for (int j = 0; j < 4; ++j) {
                    float v = fmaxf(x2v[j] - 2.f * acc[i][j][r] + p2v, 0.f);
                    __builtin_nontemporal_store(v, &dists[dbase[j] + (size_t)p * NHW]);
                    if (bj[j] == b0h) mn0 = fminf(mn0, v); else mn1 = fminf(mn1, v);
                }
                #pragma unroll
                for (int off = 1; off < 16; off <<= 1) {
                    mn0 = fminf(mn0, __shfl_xor(mn0, off, 64));
                    mn1 = fminf(mn1, __shfl_xor(mn1, off, 64));
                }
                if (lm == 0) {
                    atomicMin(&mind[b0h * NP + p], __float_as_uint(mn0));
                    if (b1h != b0h) atomicMin(&mind[b1h * NP + p], __float_as_uint(mn1));
                }
            }
        }
    }
}

// ---------- activations ----------
__global__ void act_kernel(const float* __restrict__ mind, float* __restrict__ act) {
    int i = blockIdx.x * 256 + threadIdx.x;
    if (i < NB * NP) { float md = mind[i]; act[i] = logf((md + 1.f) / (md + EPSV)); }
}

// ---------- logits = act @ fc^T ----------
__global__ void logits_kernel(const float* __restrict__ act,
                              const float* __restrict__ fc, float* __restrict__ out) {
    int r = blockIdx.x * 4 + (threadIdx.x >> 6);
    int l = threadIdx.x & 63;
    int b = r / NCL, n = r - b * NCL;
    const float* arow = act + b * NP;
    const float* frow = fc + n * NP;
    float s = 0.f;
    for (int k = l; k < NP; k += 64) s += arow[k] * frow[k];
    for (int off = 32; off; off >>= 1) s += __shfl_down(s, off, 64);
    if (l == 0) out[r] = s;
}

// ---------- x passthrough (fallback path only) ----------
__global__ void copy_kernel(const f32x4* __restrict__ in, f32x4* __restrict__ out, int n4) {
    for (int i = blockIdx.x * blockDim.x + threadIdx.x; i < n4; i += gridDim.x * blockDim.x) {
        f32x4 v = __builtin_nontemporal_load(&in[i]);
        __builtin_nontemporal_store(v, &out[i]);
    }
}

extern "C" void kernel_launch(void* const* d_in, const int* in_sizes, int n_in,
                              void* d_out, int out_size, void* d_ws, size_t ws_size,
                              hipStream_t stream) {
    const float* x     = (const float*)d_in[0];
    const float* proto = (const float*)d_in[1];
    const float* fc    = (const float*)d_in[2];
    float* out = (float*)d_out;

    // ws layout: ph (2MB) | p2 (8KB) | x2 (50KB) | [xh (12.85MB) if it fits]
    ushort_t* ph = (ushort_t*)d_ws;
    float*    p2 = (float*)(ph + (size_t)NPAD * NC);
    float*    x2 = p2 + NPAD;
    ushort_t* xh_ws = (ushort_t*)(x2 + MM);
    const size_t ws_need = (size_t)NPAD * NC * 2 + NPAD * 4 + MM * 4 + (size_t)XTOT * 2;
    const bool xh_in_ws = ws_size >= ws_need;   // ws_size constant per harness -> deterministic

    ushort_t* xh = xh_in_ws ? xh_ws : (ushort_t*)out;  // fallback: x-output region, copy runs last

    float* mind  = out + OFF_MIN;
    float* dists = out + OFF_D;
    float* act   = out + OFF_ACT;
    float* logit = out + OFF_LOG;

    splitp_kernel<<<512, 256, 0, stream>>>(proto, ph, p2, mind, x2);  // also inits mind/x2
    splitx_kernel<<<512, 256, 0, stream>>>(x, xh, x2, out, xh_in_ws ? 1 : 0);

    gemm_kernel<<<1568, 256, 0, stream>>>(xh, ph, p2, x2, dists, (unsigned*)mind);

    act_kernel<<<500, 256, 0, stream>>>(mind, act);
    logits_kernel<<<3200, 256, 0, stream>>>(act, fc, logit);

    if (!xh_in_ws)
        copy_kernel<<<2048, 256, 0, stream>>>((const f32x4*)x, (f32x4*)out, XTOT / 4);
}